// Round 10
// baseline (66.696 us; speedup 1.0000x reference)
//
#include <hip/hip_runtime.h>

// Conv2d 7x7 s2 p3, 1ch, 8192^2 fp32 -> 4096^2 fp32.
// 256x16 output tile / 256-thread block, 4 wide x 4 tall outputs per thread.
// Rationale vs r9 (256x8): same 2080B row segments, but vertical overfetch
// 1.33 -> 1.17 and LDS bytes/output 72 -> 52 (13-row window serves 4 out-rows).
// LDS: 37 rows x 130 chunks, parity-interleaved slots (even->0..64, odd->65..129);
// reads are 64 consecutive slots across a wave => conflict-free.
// Register staging, dense global reads, two phases (10+9 rounds) to cap VGPRs.
// 76KB LDS -> 2 blocks/CU. Nontemporal output stores.

#define THREADS 256
#define TILE_W 256
#define TILE_H 16
#define IN_H 37              // TILE_H*2 + 5
#define CHUNKS 130           // float4 chunks per input row (520 cols)
#define ROWF (CHUNKS * 4)    // floats per LDS row
#define NSLOT (IN_H * CHUNKS)   // 4810
#define NRA 10               // staging phase-A rounds (chunks 0..2559)
#define NRB 9                // staging phase-B rounds (chunks 2560..4863)
#define NSLOT_PAD 4864       // 19 rounds x 256 threads -> 77,824 B LDS
#define IMG 8192
#define OUTW 4096

typedef float __attribute__((ext_vector_type(4))) floatx4;

__global__ __launch_bounds__(THREADS, 2)
void conv7x7_s2(const float* __restrict__ x, const float* __restrict__ wgt,
                const float* __restrict__ bias, float* __restrict__ out) {
  __shared__ __align__(16) float lds[NSLOT_PAD * 4];
  const int t = threadIdx.x;
  const int tile_x = blockIdx.x * TILE_W;
  const int tile_y = blockIdx.y * TILE_H;
  const int g0c4 = tile_x * 2 - 4;  // aligned input col of chunk 0
  const int g0r = tile_y * 2 - 3;   // input row of LDS row 0

  float wv[49];
#pragma unroll
  for (int i = 0; i < 49; ++i) wv[i] = wgt[i];   // uniform -> SGPRs
  const float bv = bias[0];

  const bool interior = (blockIdx.x >= 1) & (blockIdx.x <= 14) &
                        (blockIdx.y >= 1) & (blockIdx.y <= 254);

  // ---- staging phase A: chunks s = t..t+2559 (all < NSLOT) ----
  {
    float4 vb[NRA];
    if (interior) {
      const float* xb = x + (long long)g0r * IMG + g0c4;
#pragma unroll
      for (int i = 0; i < NRA; ++i) {
        const int s = t + THREADS * i;
        const int r = s / CHUNKS;
        const int g = s - r * CHUNKS;
        vb[i] = *reinterpret_cast<const float4*>(xb + (long long)r * IMG + 4 * g);
      }
    } else {
#pragma unroll
      for (int i = 0; i < NRA; ++i) {
        const int s = t + THREADS * i;
        const int r = s / CHUNKS;
        const int g = s - r * CHUNKS;
        const int gr = g0r + r;
        const int gc = g0c4 + 4 * g;
        float4 v = make_float4(0.f, 0.f, 0.f, 0.f);
        if ((unsigned)gr < (unsigned)IMG && (unsigned)gc < (unsigned)(IMG - 3))
          v = *reinterpret_cast<const float4*>(&x[(long long)gr * IMG + gc]);
        vb[i] = v;
      }
    }
#pragma unroll
    for (int i = 0; i < NRA; ++i) {
      const int s = t + THREADS * i;
      const int r = s / CHUNKS;
      const int g = s - r * CHUNKS;
      const int sl = (g & 1) ? (65 + (g >> 1)) : (g >> 1);  // parity slot
      *reinterpret_cast<float4*>(&lds[(r * CHUNKS + sl) * 4]) = vb[i];
    }
  }
  // ---- staging phase B: chunks s = t+2560 .. t+4863 (guard s < NSLOT) ----
  {
    float4 vb[NRB];
    if (interior) {
      const float* xb = x + (long long)g0r * IMG + g0c4;
#pragma unroll
      for (int i = 0; i < NRB; ++i) {
        const int s = t + THREADS * (NRA + i);
        if (s < NSLOT) {
          const int r = s / CHUNKS;
          const int g = s - r * CHUNKS;
          vb[i] = *reinterpret_cast<const float4*>(xb + (long long)r * IMG + 4 * g);
        }
      }
    } else {
#pragma unroll
      for (int i = 0; i < NRB; ++i) {
        const int s = t + THREADS * (NRA + i);
        const int r = s / CHUNKS;
        const int g = s - r * CHUNKS;
        const int gr = g0r + r;
        const int gc = g0c4 + 4 * g;
        float4 v = make_float4(0.f, 0.f, 0.f, 0.f);
        if (s < NSLOT && (unsigned)gr < (unsigned)IMG &&
            (unsigned)gc < (unsigned)(IMG - 3))
          v = *reinterpret_cast<const float4*>(&x[(long long)gr * IMG + gc]);
        vb[i] = v;
      }
    }
#pragma unroll
    for (int i = 0; i < NRB; ++i) {
      const int s = t + THREADS * (NRA + i);
      if (s < NSLOT) {
        const int r = s / CHUNKS;
        const int g = s - r * CHUNKS;
        const int sl = (g & 1) ? (65 + (g >> 1)) : (g >> 1);
        *reinterpret_cast<float4*>(&lds[(r * CHUNKS + sl) * 4]) = vb[i];
      }
    }
  }
  __syncthreads();

  // ---- compute: 4 wide x 4 tall per thread ----
  const int tx = t & 63;          // 0..63 -> 256 output cols (wave = one ty)
  const int ty = t >> 6;          // 0..3  -> 4 output rows each
  float acc[4][4];
#pragma unroll
  for (int y = 0; y < 4; ++y)
#pragma unroll
    for (int xx = 0; xx < 4; ++xx) acc[y][xx] = bv;

#pragma unroll
  for (int j = 0; j < 13; ++j) {
    const int slr = 8 * ty + j;   // LDS input row, max 36
    const float* rp = &lds[slr * ROWF];
    float rbuf[16];
    // chunks 2tx..2tx+3 -> slots tx, 65+tx, tx+1, 66+tx (dense across wave)
    {
      const float4 v0 = *reinterpret_cast<const float4*>(rp + (tx) * 4);
      const float4 v1 = *reinterpret_cast<const float4*>(rp + (65 + tx) * 4);
      const float4 v2 = *reinterpret_cast<const float4*>(rp + (tx + 1) * 4);
      const float4 v3 = *reinterpret_cast<const float4*>(rp + (66 + tx) * 4);
      rbuf[0] = v0.x;  rbuf[1] = v0.y;  rbuf[2] = v0.z;  rbuf[3] = v0.w;
      rbuf[4] = v1.x;  rbuf[5] = v1.y;  rbuf[6] = v1.z;  rbuf[7] = v1.w;
      rbuf[8] = v2.x;  rbuf[9] = v2.y;  rbuf[10] = v2.z; rbuf[11] = v2.w;
      rbuf[12] = v3.x; rbuf[13] = v3.y; rbuf[14] = v3.z; rbuf[15] = v3.w;
    }
    // rbuf[i] = input col (8tx+i) rel. to g0c4; out col 4tx+xx needs 8tx+2xx+kw+1
#pragma unroll
    for (int y = 0; y < 4; ++y) {
      const int kh = j - 2 * y;   // compile-time after unroll
      if (kh >= 0 && kh <= 6) {
#pragma unroll
        for (int xx = 0; xx < 4; ++xx)
#pragma unroll
          for (int kw = 0; kw < 7; ++kw)
            acc[y][xx] = fmaf(rbuf[2 * xx + kw + 1], wv[kh * 7 + kw], acc[y][xx]);
      }
    }
  }

  // ---- store: 4 x nontemporal dwordx4, 1KB contiguous per wave-row ----
  const int ox = tile_x + 4 * tx;
  const int oy0 = tile_y + 4 * ty;
#pragma unroll
  for (int y = 0; y < 4; ++y) {
    floatx4 v;
    v.x = acc[y][0]; v.y = acc[y][1]; v.z = acc[y][2]; v.w = acc[y][3];
    __builtin_nontemporal_store(
        v, reinterpret_cast<floatx4*>(&out[(long long)(oy0 + y) * OUTW + ox]));
  }
}

extern "C" void kernel_launch(void* const* d_in, const int* in_sizes, int n_in,
                              void* d_out, int out_size, void* d_ws, size_t ws_size,
                              hipStream_t stream) {
  const float* x = (const float*)d_in[0];
  const float* w = (const float*)d_in[1];
  const float* b = (const float*)d_in[2];
  float* out = (float*)d_out;
  dim3 grid(OUTW / TILE_W, OUTW / TILE_H);  // 16 x 256
  conv7x7_s2<<<grid, dim3(THREADS), 0, stream>>>(x, w, b, out);
}

// Round 11
// 59.317 us; speedup vs baseline: 1.1244x; 1.1244x over previous
//
#include <hip/hip_runtime.h>

// Conv2d 7x7 s2 p3, 1ch, 8192^2 fp32 -> 4096^2 fp32.
// r9 config (best: 64.6us) + T1 XCD-aware block swizzle ONLY.
// 256x8 output tile / 256-thread block, 4x2 outputs per thread.
// Swizzle: bid=bx+16*by; xcd=bid&7 owns tile-columns {2*xcd, 2*xcd+1},
// walking by fastest -> each XCD's concurrent blocks form a 520-col x
// ~1550-row input strip (~3.2MB) that fits its 4MB L2; vertical halo
// re-reads become L2 hits. Bijective (8192 % 8 == 0).
// LDS: 21 rows x 130 chunks, parity-interleaved slots; conflict-free reads.
// Register staging, dense global reads; nontemporal output stores.

#define THREADS 256
#define TILE_W 256
#define TILE_H 8
#define IN_H 21              // TILE_H*2 + 5
#define CHUNKS 130           // float4 chunks per input row (520 cols)
#define ROWF (CHUNKS * 4)    // floats per LDS row
#define NSLOT (IN_H * CHUNKS)   // 2730
#define NROUND 11               // ceil(2730/256)
#define NSLOT_PAD (NROUND * THREADS)  // 2816 chunks -> 45056 B LDS
#define IMG 8192
#define OUTW 4096
#define GRIDX 16

typedef float __attribute__((ext_vector_type(4))) floatx4;

__global__ __launch_bounds__(THREADS, 3)
void conv7x7_s2(const float* __restrict__ x, const float* __restrict__ wgt,
                const float* __restrict__ bias, float* __restrict__ out) {
  __shared__ __align__(16) float lds[NSLOT_PAD * 4];
  const int t = threadIdx.x;

  // ---- XCD-aware swizzle: bid -> (bx, by), by fastest within an XCD ----
  const int bid = blockIdx.x + GRIDX * blockIdx.y;  // dispatch-linear
  const int xcd = bid & 7;
  const int local = bid >> 3;            // 0..1023 per XCD
  const int bx = 2 * xcd + (local >> 9); // 2 tile-columns per XCD
  const int by = local & 511;

  const int tile_x = bx * TILE_W;
  const int tile_y = by * TILE_H;
  const int g0c4 = tile_x * 2 - 4;  // aligned input col of chunk 0
  const int g0r = tile_y * 2 - 3;   // input row of LDS row 0

  float wv[49];
#pragma unroll
  for (int i = 0; i < 49; ++i) wv[i] = wgt[i];   // uniform -> SGPRs
  const float bv = bias[0];

  const bool interior = (bx >= 1) & (bx <= 14) & (by >= 1) & (by <= 510);

  // ---- staging: dense global loads -> regs, parity-scattered ds_writes ----
  float4 vbuf[NROUND];
  if (interior) {
    const float* xb = x + (long long)g0r * IMG + g0c4;
#pragma unroll
    for (int i = 0; i < NROUND; ++i) {
      const int s = t + THREADS * i;      // dense: lane-consecutive chunks
      if (s < NSLOT) {
        const int r = s / CHUNKS;          // magic-mul div
        const int g = s - r * CHUNKS;      // global chunk within row
        vbuf[i] = *reinterpret_cast<const float4*>(xb + (long long)r * IMG + 4 * g);
      }
    }
  } else {
#pragma unroll
    for (int i = 0; i < NROUND; ++i) {
      const int s = t + THREADS * i;
      const int r = s / CHUNKS;
      const int g = s - r * CHUNKS;
      const int gr = g0r + r;
      const int gc = g0c4 + 4 * g;
      float4 v = make_float4(0.f, 0.f, 0.f, 0.f);
      if (s < NSLOT && (unsigned)gr < (unsigned)IMG &&
          (unsigned)gc < (unsigned)(IMG - 3))
        v = *reinterpret_cast<const float4*>(&x[(long long)gr * IMG + gc]);
      vbuf[i] = v;
    }
  }
#pragma unroll
  for (int i = 0; i < NROUND; ++i) {
    const int s = t + THREADS * i;
    if (s < NSLOT) {
      const int r = s / CHUNKS;
      const int g = s - r * CHUNKS;
      const int sl = (g & 1) ? (65 + (g >> 1)) : (g >> 1);  // parity slot
      *reinterpret_cast<float4*>(&lds[(r * CHUNKS + sl) * 4]) = vbuf[i];
    }
  }
  __syncthreads();

  // ---- compute: 4 wide x 2 tall per thread ----
  const int tx = t & 63;          // 0..63 -> 256 output cols
  const int ty = t >> 6;          // 0..3  -> 2 output rows each
  float acc[2][4];
#pragma unroll
  for (int y = 0; y < 2; ++y)
#pragma unroll
    for (int xx = 0; xx < 4; ++xx) acc[y][xx] = bv;

#pragma unroll
  for (int j = 0; j < 9; ++j) {
    const int sl = 4 * ty + j;    // LDS input row, max 20
    const float* rp = &lds[sl * ROWF];
    float rbuf[16];
    // chunks 2tx..2tx+3 -> slots tx, 65+tx, tx+1, 66+tx (dense across wave)
    {
      const float4 v0 = *reinterpret_cast<const float4*>(rp + (tx) * 4);
      const float4 v1 = *reinterpret_cast<const float4*>(rp + (65 + tx) * 4);
      const float4 v2 = *reinterpret_cast<const float4*>(rp + (tx + 1) * 4);
      const float4 v3 = *reinterpret_cast<const float4*>(rp + (66 + tx) * 4);
      rbuf[0] = v0.x;  rbuf[1] = v0.y;  rbuf[2] = v0.z;  rbuf[3] = v0.w;
      rbuf[4] = v1.x;  rbuf[5] = v1.y;  rbuf[6] = v1.z;  rbuf[7] = v1.w;
      rbuf[8] = v2.x;  rbuf[9] = v2.y;  rbuf[10] = v2.z; rbuf[11] = v2.w;
      rbuf[12] = v3.x; rbuf[13] = v3.y; rbuf[14] = v3.z; rbuf[15] = v3.w;
    }
    // rbuf[i] = input col (8tx+i) rel. to g0c4; out col 4tx+xx needs 8tx+2xx+kw+1
#pragma unroll
    for (int y = 0; y < 2; ++y) {
      const int kh = j - 2 * y;
      if (kh >= 0 && kh <= 6) {
#pragma unroll
        for (int xx = 0; xx < 4; ++xx)
#pragma unroll
          for (int kw = 0; kw < 7; ++kw)
            acc[y][xx] = fmaf(rbuf[2 * xx + kw + 1], wv[kh * 7 + kw], acc[y][xx]);
      }
    }
  }

  // ---- store: nontemporal, 1KB contiguous per wave-row ----
  const int ox = tile_x + 4 * tx;
  const int oy = tile_y + 2 * ty;
#pragma unroll
  for (int y = 0; y < 2; ++y) {
    floatx4 v;
    v.x = acc[y][0]; v.y = acc[y][1]; v.z = acc[y][2]; v.w = acc[y][3];
    __builtin_nontemporal_store(
        v, reinterpret_cast<floatx4*>(&out[(long long)(oy + y) * OUTW + ox]));
  }
}

extern "C" void kernel_launch(void* const* d_in, const int* in_sizes, int n_in,
                              void* d_out, int out_size, void* d_ws, size_t ws_size,
                              hipStream_t stream) {
  const float* x = (const float*)d_in[0];
  const float* w = (const float*)d_in[1];
  const float* b = (const float*)d_in[2];
  float* out = (float*)d_out;
  dim3 grid(GRIDX, OUTW / TILE_H);  // 16 x 512
  conv7x7_s2<<<grid, dim3(THREADS), 0, stream>>>(x, w, b, out);
}